// Round 8
// baseline (208.380 us; speedup 1.0000x reference)
//
#include <hip/hip_runtime.h>

// conv_layer: out[b,v,o] = sum_{j<7,c<64} x[b, neigh[v*7+j], c] * W[o, j*64+c] + b[o]
// B=2, V=163842, C_IN=C_OUT=64, K=448. bf16 MFMA gather-GEMM.
// R8 (= R6 resubmit; two infra timeouts): batch-paired waves (both batches share
// neigh), L3 warm-read of xbf, LDS-bounce coalesced epilogue.

constexpr int V_ICO   = 163842;
constexpr int M_TOTAL = 2 * V_ICO;        // 327684
constexpr int X_ELEMS = M_TOTAL * 64;     // 20,971,776
constexpr int W_ELEMS = 64 * 448;         // 28,672
constexpr int XCH     = X_ELEMS / 8;      // 16B bf16 chunks of x
constexpr int WCH     = W_ELEMS / 8;      // 3584
constexpr int GRID_MM = (V_ICO + 255) / 256;   // 641 blocks, 256 vertices each

typedef __attribute__((ext_vector_type(4))) float          f32x4;
typedef __attribute__((ext_vector_type(4))) unsigned int   u32x4;
typedef __attribute__((ext_vector_type(8))) unsigned short u16x8;
typedef __attribute__((ext_vector_type(8))) __bf16         bf16x8;

union BF8 { u32x4 q; u16x8 u; bf16x8 v; };

static __device__ __forceinline__ unsigned short f2bf(float f) {
  unsigned int t = __float_as_uint(f);
  t += 0x7FFFu + ((t >> 16) & 1u);   // round-to-nearest-even
  return (unsigned short)(t >> 16);
}

static __device__ __forceinline__ u32x4 cvt8(f32x4 a, f32x4 b) {
  BF8 r;
  r.u[0] = f2bf(a[0]); r.u[1] = f2bf(a[1]); r.u[2] = f2bf(a[2]); r.u[3] = f2bf(a[3]);
  r.u[4] = f2bf(b[0]); r.u[5] = f2bf(b[1]); r.u[6] = f2bf(b[2]); r.u[7] = f2bf(b[3]);
  return r.q;
}

// fp32 -> bf16 for x (and W appended). One 16B-out chunk per thread.
__global__ __launch_bounds__(256)
void cvt_x_w(const float* __restrict__ x, const float* __restrict__ W,
             u32x4* __restrict__ xbf, u32x4* __restrict__ wbf) {
  const int i = blockIdx.x * blockDim.x + threadIdx.x;
  if (i >= XCH + WCH) return;
  const f32x4* src;
  u32x4* dst;
  if (i < XCH) {
    src = reinterpret_cast<const f32x4*>(x) + 2 * (size_t)i;
    dst = xbf + i;
  } else {
    const int k = i - XCH;
    src = reinterpret_cast<const f32x4*>(W) + 2 * (size_t)k;
    dst = wbf + k;
  }
  f32x4 f0 = src[0], f1 = src[1];
  *dst = cvt8(f0, f1);
}

__global__ __launch_bounds__(256)
void cvt_w_only(const float* __restrict__ W, u32x4* __restrict__ wbf) {
  const int i = blockIdx.x * blockDim.x + threadIdx.x;
  if (i < WCH) {
    const f32x4* src = reinterpret_cast<const f32x4*>(W) + 2 * (size_t)i;
    f32x4 f0 = src[0], f1 = src[1];
    wbf[i] = cvt8(f0, f1);
  }
}

// Read-warm xbf so its lines are L3-resident before the gather.
__global__ __launch_bounds__(256)
void warm_l3(const u32x4* __restrict__ p, int nchunks) {
  unsigned int a0 = 0, a1 = 0, a2 = 0, a3 = 0;
  const int stride = gridDim.x * blockDim.x;
  for (int i = blockIdx.x * blockDim.x + threadIdx.x; i < nchunks; i += stride) {
    u32x4 v = p[i];
    a0 ^= v[0]; a1 ^= v[1]; a2 ^= v[2]; a3 ^= v[3];
  }
  asm volatile("" :: "v"(a0), "v"(a1), "v"(a2), "v"(a3));   // keep loads live
}

// Main gather-GEMM, batch-paired. Block = 1024 threads = 16 waves; each wave owns
// 16 vertices x BOTH batches (32 output rows), all 64 out channels.
// LDS: W 57344 B (fragment-ordered) + bounce 16 x 16 x 272 B = 69632 B.
template <int XBF, int WPRE>
__global__ __launch_bounds__(1024, 4)
void gather_mm(const float* __restrict__ x32, const unsigned short* __restrict__ x16,
               const int* __restrict__ neigh,
               const float* __restrict__ W32, const unsigned short* __restrict__ W16,
               const float* __restrict__ bias, float* __restrict__ out) {
  __shared__ __align__(16) unsigned short Wlds[WCH * 8];   // 57344 B
  __shared__ __align__(16) float Bounce[16][16][68];       // 69632 B

  const int tid  = threadIdx.x;
  const int w    = tid >> 6;      // wave 0..15
  const int lane = tid & 63;
  const int r    = lane & 15;
  const int g    = lane >> 4;     // k-group 0..3
  const int v0   = blockIdx.x * 256 + w * 16;

  int vA = v0 + r;
  if (vA > V_ICO - 1) vA = V_ICO - 1;   // clamp for safe index loads

  int nofs[7];
#pragma unroll
  for (int j = 0; j < 7; ++j) nofs[j] = neigh[vA * 7 + j];

  // Stage W, fragment-ordered: chunk i = (kc*4+nt)*64 + l holds
  // W[nt*16 + (l&15)][kc*32 + (l>>4)*8 .. +8].
  for (int i = tid; i < WCH; i += 1024) {
    const int kcnt = i >> 6;
    const int l    = i & 63;
    const int row  = ((kcnt & 3) << 4) | (l & 15);
    u32x4 val;
    if constexpr (WPRE) {
      const int c8 = ((kcnt >> 2) << 2) + (l >> 4);
      val = reinterpret_cast<const u32x4*>(W16)[row * 56 + c8];
    } else {
      const int col = ((kcnt >> 2) << 5) + ((l >> 4) << 3);
      const f32x4* p = reinterpret_cast<const f32x4*>(W32 + row * 448 + col);
      val = cvt8(p[0], p[1]);
    }
    *reinterpret_cast<u32x4*>(&Wlds[(size_t)i * 8]) = val;
  }
  __syncthreads();
  if (v0 >= V_ICO) return;        // after the only barrier: legal

  const unsigned short* wp = Wlds + (lane << 3);   // + (kc*4+nt)*512 imm offsets

  const f32x4 zero = {0.f, 0.f, 0.f, 0.f};
  f32x4 aA0 = zero, aA1 = zero, aA2 = zero, aA3 = zero;   // batch 0
  f32x4 aB0 = zero, aB1 = zero, aB2 = zero, aB3 = zero;   // batch 1

#define FR(kc, nt) (*reinterpret_cast<const bf16x8*>(wp + ((kc) * 4 + (nt)) * 512))

  // One neighbor j: s0/s1 = batch0 lo/hi k-chunk frags, s2/s3 = batch1.
#define COMPJ(s0, s1, s2, s3, j) do {                                        \
    __builtin_amdgcn_s_setprio(1);                                           \
    bf16x8 f_;                                                               \
    f_ = FR(2*(j), 0);                                                       \
    aA0 = __builtin_amdgcn_mfma_f32_16x16x32_bf16(s0.v, f_, aA0, 0, 0, 0);   \
    aB0 = __builtin_amdgcn_mfma_f32_16x16x32_bf16(s2.v, f_, aB0, 0, 0, 0);   \
    f_ = FR(2*(j), 1);                                                       \
    aA1 = __builtin_amdgcn_mfma_f32_16x16x32_bf16(s0.v, f_, aA1, 0, 0, 0);   \
    aB1 = __builtin_amdgcn_mfma_f32_16x16x32_bf16(s2.v, f_, aB1, 0, 0, 0);   \
    f_ = FR(2*(j), 2);                                                       \
    aA2 = __builtin_amdgcn_mfma_f32_16x16x32_bf16(s0.v, f_, aA2, 0, 0, 0);   \
    aB2 = __builtin_amdgcn_mfma_f32_16x16x32_bf16(s2.v, f_, aB2, 0, 0, 0);   \
    f_ = FR(2*(j), 3);                                                       \
    aA3 = __builtin_amdgcn_mfma_f32_16x16x32_bf16(s0.v, f_, aA3, 0, 0, 0);   \
    aB3 = __builtin_amdgcn_mfma_f32_16x16x32_bf16(s2.v, f_, aB3, 0, 0, 0);   \
    f_ = FR(2*(j)+1, 0);                                                     \
    aA0 = __builtin_amdgcn_mfma_f32_16x16x32_bf16(s1.v, f_, aA0, 0, 0, 0);   \
    aB0 = __builtin_amdgcn_mfma_f32_16x16x32_bf16(s3.v, f_, aB0, 0, 0, 0);   \
    f_ = FR(2*(j)+1, 1);                                                     \
    aA1 = __builtin_amdgcn_mfma_f32_16x16x32_bf16(s1.v, f_, aA1, 0, 0, 0);   \
    aB1 = __builtin_amdgcn_mfma_f32_16x16x32_bf16(s3.v, f_, aB1, 0, 0, 0);   \
    f_ = FR(2*(j)+1, 2);                                                     \
    aA2 = __builtin_amdgcn_mfma_f32_16x16x32_bf16(s1.v, f_, aA2, 0, 0, 0);   \
    aB2 = __builtin_amdgcn_mfma_f32_16x16x32_bf16(s3.v, f_, aB2, 0, 0, 0);   \
    f_ = FR(2*(j)+1, 3);                                                     \
    aA3 = __builtin_amdgcn_mfma_f32_16x16x32_bf16(s1.v, f_, aA3, 0, 0, 0);   \
    aB3 = __builtin_amdgcn_mfma_f32_16x16x32_bf16(s3.v, f_, aB3, 0, 0, 0);   \
    __builtin_amdgcn_s_setprio(0);                                           \
  } while (0)

  if constexpr (XBF) {
    const unsigned short* xb0 = x16 + (g << 3);
    const unsigned short* xb1 = xb0 + (size_t)V_ICO * 64;

#define LOADJ(s0, s1, s2, s3, j) do {                                        \
      const size_t ro = (size_t)nofs[j] * 64;                                \
      s0.q = *reinterpret_cast<const u32x4*>(xb0 + ro);                      \
      s1.q = *reinterpret_cast<const u32x4*>(xb0 + ro + 32);                 \
      s2.q = *reinterpret_cast<const u32x4*>(xb1 + ro);                      \
      s3.q = *reinterpret_cast<const u32x4*>(xb1 + ro + 32);                 \
    } while (0)

    BF8 pA0, pA1, pA2, pA3, pB0, pB1, pB2, pB3;
    LOADJ(pA0, pA1, pA2, pA3, 0);
    LOADJ(pB0, pB1, pB2, pB3, 1);
    COMPJ(pA0, pA1, pA2, pA3, 0); LOADJ(pA0, pA1, pA2, pA3, 2);
    COMPJ(pB0, pB1, pB2, pB3, 1); LOADJ(pB0, pB1, pB2, pB3, 3);
    COMPJ(pA0, pA1, pA2, pA3, 2); LOADJ(pA0, pA1, pA2, pA3, 4);
    COMPJ(pB0, pB1, pB2, pB3, 3); LOADJ(pB0, pB1, pB2, pB3, 5);
    COMPJ(pA0, pA1, pA2, pA3, 4); LOADJ(pA0, pA1, pA2, pA3, 6);
    COMPJ(pB0, pB1, pB2, pB3, 5);
    COMPJ(pA0, pA1, pA2, pA3, 6);
#undef LOADJ
  } else {
    // fp32 fallback (unused when ws fits): per-lane loads, depth-1.
    const float* xb0 = x32 + (g << 3);
    const float* xb1 = xb0 + (size_t)V_ICO * 64;
#pragma unroll
    for (int j = 0; j < 7; ++j) {
      const size_t ro = (size_t)nofs[j] * 64;
      BF8 s0, s1, s2, s3;
      const f32x4* p = reinterpret_cast<const f32x4*>(xb0 + ro);
      s0.q = cvt8(p[0], p[1]);
      p = reinterpret_cast<const f32x4*>(xb0 + ro + 32);
      s1.q = cvt8(p[0], p[1]);
      p = reinterpret_cast<const f32x4*>(xb1 + ro);
      s2.q = cvt8(p[0], p[1]);
      p = reinterpret_cast<const f32x4*>(xb1 + ro + 32);
      s3.q = cvt8(p[0], p[1]);
      COMPJ(s0, s1, s2, s3, j);
    }
  }
#undef COMPJ
#undef FR

  // Epilogue: bounce through LDS so each store instr writes 1KB contiguous.
  // C/D layout: col = lane&15 (= r -> channel low), row = g*4 + reg.
  float* bw = &Bounce[w][0][0];
  const f32x4 biasf = *reinterpret_cast<const f32x4*>(bias + (r << 2));
  const bool full = (v0 + 16 <= V_ICO);

  auto epilogue = [&](const f32x4& A0, const f32x4& A1, const f32x4& A2,
                      const f32x4& A3, size_t rowbase) {
#pragma unroll
    for (int q2 = 0; q2 < 4; ++q2) {
      bw[(g * 4 + q2) * 68 +  0 + r] = A0[q2];
      bw[(g * 4 + q2) * 68 + 16 + r] = A1[q2];
      bw[(g * 4 + q2) * 68 + 32 + r] = A2[q2];
      bw[(g * 4 + q2) * 68 + 48 + r] = A3[q2];
    }
    asm volatile("s_waitcnt lgkmcnt(0)" ::: "memory");
#pragma unroll
    for (int q2 = 0; q2 < 4; ++q2) {
      const int rowIt = g * 4 + q2;
      f32x4 v = *reinterpret_cast<const f32x4*>(&bw[rowIt * 68 + (r << 2)]);
      v = v + biasf;
      if (full || v0 + rowIt < V_ICO) {
        __builtin_nontemporal_store(
            v, reinterpret_cast<f32x4*>(out + (rowbase + rowIt) * 64 + (r << 2)));
      }
    }
    asm volatile("s_waitcnt lgkmcnt(0)" ::: "memory");  // reads done before reuse
  };

  epilogue(aA0, aA1, aA2, aA3, (size_t)v0);
  epilogue(aB0, aB1, aB2, aB3, (size_t)V_ICO + v0);
}

extern "C" void kernel_launch(void* const* d_in, const int* in_sizes, int n_in,
                              void* d_out, int out_size, void* d_ws, size_t ws_size,
                              hipStream_t stream) {
  const float* x    = (const float*)d_in[0];
  const int*   nbr  = (const int*)d_in[1];
  const float* W    = (const float*)d_in[2];
  const float* bias = (const float*)d_in[3];
  float* out = (float*)d_out;

  const size_t xbf_bytes = (size_t)X_ELEMS * 2;
  const size_t wbf_bytes = (size_t)W_ELEMS * 2;

  if (ws_size >= xbf_bytes + wbf_bytes) {
    u32x4* xbf = (u32x4*)d_ws;
    u32x4* wbf = (u32x4*)((char*)d_ws + xbf_bytes);
    hipLaunchKernelGGL(cvt_x_w, dim3((XCH + WCH + 255) / 256), dim3(256), 0, stream,
                       x, W, xbf, wbf);
    hipLaunchKernelGGL(warm_l3, dim3(2048), dim3(256), 0, stream,
                       (const u32x4*)xbf, XCH);
    hipLaunchKernelGGL((gather_mm<1, 1>), dim3(GRID_MM), dim3(1024), 0, stream,
                       x, (const unsigned short*)xbf, nbr,
                       W, (const unsigned short*)wbf, bias, out);
  } else if (ws_size >= wbf_bytes) {
    u32x4* wbf = (u32x4*)d_ws;
    hipLaunchKernelGGL(cvt_w_only, dim3((WCH + 255) / 256), dim3(256), 0, stream, W, wbf);
    hipLaunchKernelGGL((gather_mm<0, 1>), dim3(GRID_MM), dim3(1024), 0, stream,
                       x, nullptr, nbr, W, (const unsigned short*)wbf, bias, out);
  } else {
    hipLaunchKernelGGL((gather_mm<0, 0>), dim3(GRID_MM), dim3(1024), 0, stream,
                       x, nullptr, nbr, W, nullptr, bias, out);
  }
}